// Round 14
// baseline (190.902 us; speedup 1.0000x reference)
//
#include <hip/hip_runtime.h>

// QLinear: y[n,o] = round((sum_k (x[n,k]-xz)*(w[o,k]-wz) + bias[o]) * M + yz)
// N=65536, K=512, OUT=512.
// Exact i8 path: (x-128),(w-128) in [-128,127]; |dot+bias| < 2^24; f32 epilogue exact.
// R14 = R13 with the WAR ordering bug fixed: consume ra[t&1] (convA) BEFORE
// loadA(t+2) overwrites the set. Wave-autonomous: no LDS, no barriers, no drains.
//   - wave = 16 rows x 128 cols. A frag per-lane in regs (R2/R4-validated layout).
//   - B: 8 frags/K-step from L2-resident W, register double-buffered, consumed
//     one step after issue. VGPR_Count ~150 expected (<=80 would mean remat).

#define K_DIM 512
#define OUTF  512
#define NT    8                   // K_DIM / 64

typedef __attribute__((ext_vector_type(4))) int   i32x4;
typedef __attribute__((ext_vector_type(4))) float f32x4;

// ---------- prepass: weight int32 -> i8 (w - wz), row-major [o][k] ----------
__global__ void wprep(const int* __restrict__ W, unsigned int* __restrict__ Wb,
                      const float* __restrict__ wzp) {
    const int wz = __float2int_rn(wzp[0]);
    int idx = (blockIdx.x * blockDim.x + threadIdx.x) * 4;
    i32x4 w = *reinterpret_cast<const i32x4*>(W + idx);
    unsigned int p = ((unsigned int)(w[0] - wz) & 0xffu)
                   | (((unsigned int)(w[1] - wz) & 0xffu) << 8)
                   | (((unsigned int)(w[2] - wz) & 0xffu) << 16)
                   | (((unsigned int)(w[3] - wz) & 0xffu) << 24);
    Wb[idx >> 2] = p;
}

__global__ __launch_bounds__(256, 3)
void qgemm(const float* __restrict__ X,
           const unsigned char* __restrict__ Wb,
           const int* __restrict__ bias,
           const float* __restrict__ Mp,
           const float* __restrict__ xzp,
           const float* __restrict__ yzp,
           float* __restrict__ Y) {
    const int tid  = threadIdx.x;
    const int lane = tid & 63;
    const int wid  = tid >> 6;              // 0..3 -> col strip 128*wid
    const int fr   = lane & 15;
    const int fq   = lane >> 4;

    const int row0 = blockIdx.x * 16;       // 4 waves share these 16 x-rows (L1)
    const int c0   = wid * 128;

    const float xzf = xzp[0];

    // A: lane owns x row (row0+fr), k-window fq*16 (+t*64): 16 consecutive f32.
    const float* xb = X + (size_t)(row0 + fr) * K_DIM + fq * 16;
    // B: frag n: lane owns W row (c0+n*16+fr), same k-window.
    const unsigned char* wb = Wb + (size_t)(c0 + fr) * K_DIM + fq * 16;

    f32x4 ra[2][4];                         // A staging, distance 2
    i32x4 rb[2][8];                         // B batch, double-buffered (64 VGPR)

    auto loadA = [&](int t) {
        const float* p = xb + t * 64;
        #pragma unroll
        for (int q = 0; q < 4; ++q)
            ra[t & 1][q] = *reinterpret_cast<const f32x4*>(p + q * 4);
    };
    auto loadB = [&](int t) {
        const unsigned char* p = wb + t * 64;
        #pragma unroll
        for (int n = 0; n < 8; ++n)
            rb[t & 1][n] = *reinterpret_cast<const i32x4*>(p + (size_t)n * 16 * K_DIM);
    };

    // bias folded into accumulator init
    i32x4 acc[8];
    #pragma unroll
    for (int n = 0; n < 8; ++n) {
        const int bv = bias[c0 + n * 16 + fr];
        acc[n] = i32x4{bv, bv, bv, bv};
    }

    // prologue: A(0),A(1) and B(0) in flight
    loadA(0);
    loadA(1);
    loadB(0);

    #pragma unroll
    for (int t = 0; t < NT; ++t) {
        if (t + 1 < NT) loadB(t + 1);       // other rb buffer: no collision

        // consume A(t) FIRST (loads 2 iterations old) -- then its set is free
        i32x4 af;
        #pragma unroll
        for (int q = 0; q < 4; ++q) {
            const f32x4 v = ra[t & 1][q];
            unsigned int u0 = (unsigned int)((int)(v[0] - xzf)) & 0xffu;
            unsigned int u1 = (unsigned int)((int)(v[1] - xzf)) & 0xffu;
            unsigned int u2 = (unsigned int)((int)(v[2] - xzf)) & 0xffu;
            unsigned int u3 = (unsigned int)((int)(v[3] - xzf)) & 0xffu;
            af[q] = (int)(u0 | (u1 << 8) | (u2 << 16) | (u3 << 24));
        }

        if (t + 2 < NT) loadA(t + 2);       // NOW safe to reissue this set

        // 8 MFMA on B(t) (issued 1 step ago; latency hidden by conv + TLP)
        #pragma unroll
        for (int n = 0; n < 8; ++n)
            acc[n] = __builtin_amdgcn_mfma_i32_16x16x64_i8(af, rb[t & 1][n], acc[n], 0, 0, 0);
    }

    // epilogue: y = rintf(acc * M + yz)  (bias pre-folded)
    const float Mv = Mp[0], yz = yzp[0];
    #pragma unroll
    for (int j = 0; j < 4; ++j) {
        const int row = row0 + fq * 4 + j;
        float* yp = Y + (size_t)row * OUTF + c0 + fr;
        #pragma unroll
        for (int n = 0; n < 8; ++n)
            yp[n * 16] = rintf((float)acc[n][j] * Mv + yz);
    }
}

extern "C" void kernel_launch(void* const* d_in, const int* in_sizes, int n_in,
                              void* d_out, int out_size, void* d_ws, size_t ws_size,
                              hipStream_t stream) {
    const float* x    = (const float*)d_in[0];
    const int*   w    = (const int*)d_in[1];
    const int*   bias = (const int*)d_in[2];
    const float* M    = (const float*)d_in[3];
    const float* xz   = (const float*)d_in[4];
    const float* wz   = (const float*)d_in[5];
    const float* yz   = (const float*)d_in[6];
    float* y = (float*)d_out;

    unsigned int* Wb = (unsigned int*)d_ws;     // 512*512 i8 = 256 KB

    wprep<<<256, 256, 0, stream>>>(w, Wb, wz);
    qgemm<<<4096, 256, 0, stream>>>(x, (const unsigned char*)Wb, bias, M, xz, yz, y);
}

// Round 15
// 101.263 us; speedup vs baseline: 1.8852x; 1.8852x over previous
//
#include <hip/hip_runtime.h>

// QLinear: y[n,o] = round((sum_k (x[n,k]-xz)*(w[o,k]-wz) + bias[o]) * M + yz)
// N=65536, K=512, OUT=512.
// Exact i8 path: (x-128),(w-128) in [-128,127]; |dot+bias| < 2^24; f32 epilogue exact.
// R15: producer/consumer wave specialization (the anti-2-phase structure).
//   8 waves: 4 producers (global->regs->convert->LDS + gload_lds B, no MFMA),
//            4 consumers (ds_read + MFMA, no global traffic). 1P+1C per SIMD.
//   Triple-buffered LDS: consumers read buf t; producers conv-write t+1, gload t+2.
//   Raw s_barrier + counted vmcnt(10): 10 loads stay in flight across every barrier.

#define K_DIM 512
#define OUTF  512
#define NT    8                   // K_DIM / 64

typedef __attribute__((ext_vector_type(4))) int   i32x4;
typedef __attribute__((ext_vector_type(4))) float f32x4;

__device__ __forceinline__ void gload16(const void* g, void* l) {
    __builtin_amdgcn_global_load_lds(
        (const __attribute__((address_space(1))) void*)g,
        (__attribute__((address_space(3))) void*)l, 16, 0, 0);
}

// ---------- prepass: weight int32 -> i8 (w - wz), row-major [o][k] ----------
__global__ void wprep(const int* __restrict__ W, unsigned int* __restrict__ Wb,
                      const float* __restrict__ wzp) {
    const int wz = __float2int_rn(wzp[0]);
    int idx = (blockIdx.x * blockDim.x + threadIdx.x) * 4;
    i32x4 w = *reinterpret_cast<const i32x4*>(W + idx);
    unsigned int p = ((unsigned int)(w[0] - wz) & 0xffu)
                   | (((unsigned int)(w[1] - wz) & 0xffu) << 8)
                   | (((unsigned int)(w[2] - wz) & 0xffu) << 16)
                   | (((unsigned int)(w[3] - wz) & 0xffu) << 24);
    Wb[idx >> 2] = p;
}

__global__ __launch_bounds__(512, 4)
void qgemm(const float* __restrict__ X,
           const unsigned char* __restrict__ Wb,
           const int* __restrict__ bias,
           const float* __restrict__ Mp,
           const float* __restrict__ xzp,
           const float* __restrict__ yzp,
           float* __restrict__ Y) {
    // per buffer: A frags 0..7 at [0,8K), B frags 0..7 at [8K,16K). 3 buffers.
    __shared__ unsigned char lds[3][16384];   // 49152 B

    const int tid  = threadIdx.x;
    const int lane = tid & 63;
    const int wid  = tid >> 6;                // 0..3 producers, 4..7 consumers

    // XCD-contiguous bijective swizzle (2048 = 8 * 256); col-tile fastest
    const int b = blockIdx.x;
    const int lid = (b & 7) * 256 + (b >> 3);
    const int row0 = (lid >> 2) * 128;
    const int n0   = (lid & 3) * 128;

    if (wid < 4) {
        // ---------------- producers: tid = 0..255 ----------------
        const float xzf = xzp[0];
        const int j = tid;
        const int r = j >> 1;                 // tile row 0..127
        const int mfrag = r >> 4;             // A frag 0..7
        // A frag-major slot: lane (r&15)+32*(j&1), second b128 at +16 lanes (+256B)
        const int dA = mfrag * 1024 + ((r & 15) + 32 * (j & 1)) * 16;
        const float* xbase = X + (size_t)(row0 + r) * K_DIM + (j & 1) * 32;
        // B: producer wave wid stages frags {2wid, 2wid+1} via gload_lds
        const unsigned char* wbase =
            Wb + (size_t)(n0 + wid * 32 + (lane & 15)) * K_DIM + (lane >> 4) * 16;

        f32x4 ra[2][8];                       // 32 f32 per set, 2 sets

        auto stageA = [&](int tt) {
            const float* p = xbase + tt * 64;
            #pragma unroll
            for (int q = 0; q < 8; ++q)
                ra[tt & 1][q] = *reinterpret_cast<const f32x4*>(p + q * 4);
        };
        auto gloadB = [&](int tt) {
            unsigned char* base = &lds[tt % 3][8192 + (2 * wid) * 1024];
            const unsigned char* g = wbase + tt * 64;
            gload16(g,              base);
            gload16(g + 16 * K_DIM, base + 1024);
        };
        auto convwrite = [&](int tt) {
            int pk[8];
            #pragma unroll
            for (int w = 0; w < 8; ++w) {
                const f32x4 v = ra[tt & 1][w];
                unsigned int u0 = (unsigned int)((int)(v[0] - xzf)) & 0xffu;
                unsigned int u1 = (unsigned int)((int)(v[1] - xzf)) & 0xffu;
                unsigned int u2 = (unsigned int)((int)(v[2] - xzf)) & 0xffu;
                unsigned int u3 = (unsigned int)((int)(v[3] - xzf)) & 0xffu;
                pk[w] = (int)(u0 | (u1 << 8) | (u2 << 16) | (u3 << 24));
            }
            unsigned char* base = &lds[tt % 3][dA];
            *reinterpret_cast<i32x4*>(base)       = i32x4{pk[0], pk[1], pk[2], pk[3]};
            *reinterpret_cast<i32x4*>(base + 256) = i32x4{pk[4], pk[5], pk[6], pk[7]};
        };

        // prologue: A(0),B(0),A(1),B(1) issued; conv(0); wait B(0) only.
        stageA(0); gloadB(0); stageA(1); gloadB(1);
        convwrite(0);                          // compiler waits A(0) regs (vmcnt 12)
        __builtin_amdgcn_sched_barrier(0);
        asm volatile("s_waitcnt vmcnt(10) lgkmcnt(0)" ::: "memory");  // B(0) done
        __builtin_amdgcn_s_barrier();          // barrier #1: buf0 ready

        #pragma unroll
        for (int t = 0; t < NT - 2; ++t) {     // t = 0..5
            stageA(t + 2);                     // 8 loads
            gloadB(t + 2);                     // 2 loads -> buf[(t+2)%3]
            convwrite(t + 1);                  // waits A(t+1) regs; ds_write buf[(t+1)%3]
            __builtin_amdgcn_sched_barrier(0);
            asm volatile("s_waitcnt vmcnt(10) lgkmcnt(0)" ::: "memory"); // B(t+1) done
            __builtin_amdgcn_s_barrier();      // buf[t+1] ready; A/B(t+2) stay in flight
        }
        convwrite(NT - 1);                     // tail: conv(7)
        __builtin_amdgcn_sched_barrier(0);
        asm volatile("s_waitcnt vmcnt(0) lgkmcnt(0)" ::: "memory");   // B(7) done
        __builtin_amdgcn_s_barrier();          // buf7 ready
        __builtin_amdgcn_s_barrier();          // match consumer's final barrier
    } else {
        // ---------------- consumers ----------------
        const int q4 = wid - 4;                // 0..3
        const int wr = q4 >> 1;                // row 64-strip
        const int wc = q4 & 1;                 // col 64-strip
        const int fr = lane & 15;
        const int fq = lane >> 4;

        i32x4 acc[4][4];
        #pragma unroll
        for (int n = 0; n < 4; ++n) {
            const int bv = bias[n0 + wc * 64 + n * 16 + fr];
            #pragma unroll
            for (int m = 0; m < 4; ++m)
                acc[m][n] = i32x4{bv, bv, bv, bv};
        }

        __builtin_amdgcn_s_barrier();          // barrier #1: buf0 ready

        #pragma unroll
        for (int t = 0; t < NT; ++t) {
            const int bb = t % 3;
            i32x4 af[4], bf[4];
            #pragma unroll
            for (int m = 0; m < 4; ++m)
                af[m] = *reinterpret_cast<const i32x4*>(
                    &lds[bb][(wr * 4 + m) * 1024 + lane * 16]);
            #pragma unroll
            for (int n = 0; n < 4; ++n)
                bf[n] = *reinterpret_cast<const i32x4*>(
                    &lds[bb][8192 + (wc * 4 + n) * 1024 + lane * 16]);
            #pragma unroll
            for (int m = 0; m < 4; ++m)
                #pragma unroll
                for (int n = 0; n < 4; ++n)
                    acc[m][n] = __builtin_amdgcn_mfma_i32_16x16x64_i8(
                        af[m], bf[n], acc[m][n], 0, 0, 0);
            __builtin_amdgcn_s_barrier();      // releases buf[t] for reuse at t+3
        }

        // epilogue: y = rintf(acc * M + yz)  (bias pre-folded)
        const float Mv = Mp[0], yz = yzp[0];
        #pragma unroll
        for (int n = 0; n < 4; ++n) {
            const int col = n0 + wc * 64 + n * 16 + fr;
            #pragma unroll
            for (int m = 0; m < 4; ++m) {
                const int row = row0 + wr * 64 + m * 16 + fq * 4;
                float* yp = Y + (size_t)row * OUTF + col;
                #pragma unroll
                for (int jj = 0; jj < 4; ++jj)
                    yp[(size_t)jj * OUTF] = rintf((float)acc[m][n][jj] * Mv + yz);
            }
        }
    }
}

extern "C" void kernel_launch(void* const* d_in, const int* in_sizes, int n_in,
                              void* d_out, int out_size, void* d_ws, size_t ws_size,
                              hipStream_t stream) {
    const float* x    = (const float*)d_in[0];
    const int*   w    = (const int*)d_in[1];
    const int*   bias = (const int*)d_in[2];
    const float* M    = (const float*)d_in[3];
    const float* xz   = (const float*)d_in[4];
    const float* wz   = (const float*)d_in[5];
    const float* yz   = (const float*)d_in[6];
    float* y = (float*)d_out;

    unsigned int* Wb = (unsigned int*)d_ws;     // 512*512 i8 = 256 KB

    wprep<<<256, 256, 0, stream>>>(w, Wb, wz);
    qgemm<<<2048, 512, 0, stream>>>(x, (const unsigned char*)Wb, bias, M, xz, yz, y);
}

// Round 16
// 72.223 us; speedup vs baseline: 2.6432x; 1.4021x over previous
//
#include <hip/hip_runtime.h>

// QLinear: y[n,o] = round((sum_k (x[n,k]-xz)*(w[o,k]-wz) + bias[o]) * M + yz)
// N=65536, K=512, OUT=512.
// Exact i8 path: (x-128),(w-128) in [-128,127]; |dot+bias| < 2^24; f32 epilogue exact.
// R16 = R5 (best, 68.7us) with EXACTLY ONE change: __syncthreads() -> lgkm-only
// barrier (s_waitcnt lgkmcnt(0) + s_barrier), so the dist-2 prefetch loads are
// never drained at the barrier. (Stores are plain, per R9.) Single-variable test
// of the vmcnt(0)-drain theory on the known-best kernel.

#define K_DIM 512
#define OUTF  512
#define NT    8            // K_DIM / 64
#define LDAB  80           // LDS row stride bytes: 64 data + 16 pad (<=2-way on b128)
#define TILE_B (128 * LDAB)
#define BUF_B  (2 * TILE_B)

typedef __attribute__((ext_vector_type(4))) int   i32x4;
typedef __attribute__((ext_vector_type(4))) float f32x4;

// ---------- prepass: weight int32 -> i8 (w - wz), row-major [o][k] ----------
__global__ void wprep(const int* __restrict__ W, unsigned int* __restrict__ Wb,
                      const float* __restrict__ wzp) {
    const int wz = __float2int_rn(wzp[0]);
    int idx = (blockIdx.x * blockDim.x + threadIdx.x) * 4;
    i32x4 w = *reinterpret_cast<const i32x4*>(W + idx);
    unsigned int p = ((unsigned int)(w[0] - wz) & 0xffu)
                   | (((unsigned int)(w[1] - wz) & 0xffu) << 8)
                   | (((unsigned int)(w[2] - wz) & 0xffu) << 16)
                   | (((unsigned int)(w[3] - wz) & 0xffu) << 24);
    Wb[idx >> 2] = p;
}

__global__ __launch_bounds__(512, 4)
void qgemm(const float* __restrict__ X,
           const unsigned char* __restrict__ Wb,
           const int* __restrict__ bias,
           const float* __restrict__ Mp,
           const float* __restrict__ xzp,
           const float* __restrict__ yzp,
           float* __restrict__ Y) {
    __shared__ unsigned char lds[2 * BUF_B];   // 40960 B

    const int tid  = threadIdx.x;
    const int lane = tid & 63;
    const int wid  = tid >> 6;                 // 0..7
    const int wr   = wid >> 2;                 // row 64-strip
    const int wc   = wid & 3;                  // col 32-strip
    const int fr   = lane & 15;
    const int fq   = lane >> 4;

    // XCD-contiguous bijective swizzle (2048 = 8 * 256); col-tile fastest
    const int b = blockIdx.x;
    const int lid = (b & 7) * 256 + (b >> 3);
    const int row0 = (lid >> 2) * 128;
    const int n0   = (lid & 3) * 128;

    const float xzf = xzp[0];

    // staging maps (512 threads):
    // A tile 128x64 f32: row = tid>>2, 16 f32 at col (tid&3)*16
    // B tile 128x64 i8 : row = tid>>2, 16 B   at col (tid&3)*16
    const int srow = tid >> 2;
    const int scol = (tid & 3) * 16;
    const float* xbase = X + (size_t)(row0 + srow) * K_DIM + scol;
    const unsigned char* wbase = Wb + (size_t)(n0 + srow) * K_DIM + scol;
    const int aoff = srow * LDAB + scol;
    const int boff = TILE_B + srow * LDAB + scol;

    f32x4 ra[2][4];        // two staging sets (prefetch distance 2)
    i32x4 rb[2];

    auto stage = [&](int t) {
        const int s = t & 1;
        const float* xp = xbase + t * 64;
        #pragma unroll
        for (int q = 0; q < 4; ++q)
            ra[s][q] = *reinterpret_cast<const f32x4*>(xp + q * 4);
        rb[s] = *reinterpret_cast<const i32x4*>(wbase + t * 64);
    };
    auto convwrite = [&](int t, int buf) {
        const int s = t & 1;
        const int ab = buf * BUF_B;
        i32x4 pa;
        #pragma unroll
        for (int q = 0; q < 4; ++q) {
            unsigned int u0 = (unsigned int)((int)(ra[s][q][0] - xzf)) & 0xffu;
            unsigned int u1 = (unsigned int)((int)(ra[s][q][1] - xzf)) & 0xffu;
            unsigned int u2 = (unsigned int)((int)(ra[s][q][2] - xzf)) & 0xffu;
            unsigned int u3 = (unsigned int)((int)(ra[s][q][3] - xzf)) & 0xffu;
            pa[q] = (int)(u0 | (u1 << 8) | (u2 << 16) | (u3 << 24));
        }
        *reinterpret_cast<i32x4*>(&lds[ab + aoff]) = pa;
        *reinterpret_cast<i32x4*>(&lds[ab + boff]) = rb[s];
    };

    // bias folded into accumulator init
    const int c0 = n0 + wc * 32;
    const int bv0 = bias[c0 + fr];
    const int bv1 = bias[c0 + 16 + fr];
    i32x4 acc[4][2];
    #pragma unroll
    for (int m = 0; m < 4; ++m) {
        acc[m][0] = i32x4{bv0, bv0, bv0, bv0};
        acc[m][1] = i32x4{bv1, bv1, bv1, bv1};
    }

    const int aro = (wr * 64 + fr) * LDAB + fq * 16;
    const int bro = TILE_B + (wc * 32 + fr) * LDAB + fq * 16;

    auto compute = [&](int buf) {
        const int ab = buf * BUF_B;
        i32x4 af[4], bf[2];
        #pragma unroll
        for (int m = 0; m < 4; ++m)
            af[m] = *reinterpret_cast<const i32x4*>(&lds[ab + aro + m * 16 * LDAB]);
        #pragma unroll
        for (int n = 0; n < 2; ++n)
            bf[n] = *reinterpret_cast<const i32x4*>(&lds[ab + bro + n * 16 * LDAB]);
        #pragma unroll
        for (int m = 0; m < 4; ++m)
            #pragma unroll
            for (int n = 0; n < 2; ++n)
                acc[m][n] = __builtin_amdgcn_mfma_i32_16x16x64_i8(
                    af[m], bf[n], acc[m][n], 0, 0, 0);
    };

    // lgkm-only barrier: ds ops drained; global prefetch stays in flight.
    auto barrier = [&]() {
        asm volatile("s_waitcnt lgkmcnt(0)" ::: "memory");
        __builtin_amdgcn_s_barrier();
    };

    // prologue: t=0,1 loads in flight; write t=0 (register deps wait only t=0's loads)
    stage(0);
    stage(1);
    convwrite(0, 0);
    barrier();

    #pragma unroll
    for (int t = 0; t < NT; ++t) {
        if (t + 2 < NT) stage(t + 2);                 // far-ahead issue first
        compute(t & 1);
        if (t + 1 < NT) convwrite(t + 1, (t + 1) & 1); // consume 1-iter-old loads
        barrier();
    }

    // epilogue: y = rintf(acc * M + yz)  (bias pre-folded)
    const float Mv = Mp[0], yz = yzp[0];
    #pragma unroll
    for (int n = 0; n < 2; ++n) {
        const int col = c0 + n * 16 + fr;
        #pragma unroll
        for (int m = 0; m < 4; ++m) {
            const int row = row0 + wr * 64 + m * 16 + fq * 4;
            float* yp = Y + (size_t)row * OUTF + col;
            #pragma unroll
            for (int j = 0; j < 4; ++j)
                yp[(size_t)j * OUTF] = rintf((float)acc[m][n][j] * Mv + yz);
        }
    }
}

extern "C" void kernel_launch(void* const* d_in, const int* in_sizes, int n_in,
                              void* d_out, int out_size, void* d_ws, size_t ws_size,
                              hipStream_t stream) {
    const float* x    = (const float*)d_in[0];
    const int*   w    = (const int*)d_in[1];
    const int*   bias = (const int*)d_in[2];
    const float* M    = (const float*)d_in[3];
    const float* xz   = (const float*)d_in[4];
    const float* wz   = (const float*)d_in[5];
    const float* yz   = (const float*)d_in[6];
    float* y = (float*)d_out;

    unsigned int* Wb = (unsigned int*)d_ws;     // 512*512 i8 = 256 KB

    wprep<<<256, 256, 0, stream>>>(w, Wb, wz);
    qgemm<<<2048, 512, 0, stream>>>(x, (const unsigned char*)Wb, bias, M, xz, yz, y);
}

// Round 17
// 70.452 us; speedup vs baseline: 2.7097x; 1.0251x over previous
//
#include <hip/hip_runtime.h>

// QLinear: y[n,o] = round((sum_k (x[n,k]-xz)*(w[o,k]-wz) + bias[o]) * M + yz)
// N=65536, K=512, OUT=512.
// Exact i8 path: (x-128),(w-128) in [-128,127]; |dot+bias| < 2^24; f32 epilogue exact.
// R17 = R16 with the staging loads PINNED via inline asm.
//   Root cause found (R5/R16 VGPR_Count=40 vs ~80 declared): the compiler SANK all
//   staging loads to their convwrite use -> zero effective prefetch, full latency
//   exposed every K-step. asm volatile global_load_dwordx4 cannot be sunk/remat'd;
//   consumption gated by counted s_waitcnt vmcnt(5) + sched_barrier(0) (rule 18).
//   lgkm-only barrier (R16-proven correct): prefetch never drained.

#define K_DIM 512
#define OUTF  512
#define NT    8            // K_DIM / 64
#define LDAB  80           // LDS row stride bytes: 64 data + 16 pad (<=2-way on b128)
#define TILE_B (128 * LDAB)
#define BUF_B  (2 * TILE_B)

typedef __attribute__((ext_vector_type(4))) int   i32x4;
typedef __attribute__((ext_vector_type(4))) float f32x4;

// ---------- prepass: weight int32 -> i8 (w - wz), row-major [o][k] ----------
__global__ void wprep(const int* __restrict__ W, unsigned int* __restrict__ Wb,
                      const float* __restrict__ wzp) {
    const int wz = __float2int_rn(wzp[0]);
    int idx = (blockIdx.x * blockDim.x + threadIdx.x) * 4;
    i32x4 w = *reinterpret_cast<const i32x4*>(W + idx);
    unsigned int p = ((unsigned int)(w[0] - wz) & 0xffu)
                   | (((unsigned int)(w[1] - wz) & 0xffu) << 8)
                   | (((unsigned int)(w[2] - wz) & 0xffu) << 16)
                   | (((unsigned int)(w[3] - wz) & 0xffu) << 24);
    Wb[idx >> 2] = p;
}

__global__ __launch_bounds__(512, 4)
void qgemm(const float* __restrict__ X,
           const unsigned char* __restrict__ Wb,
           const int* __restrict__ bias,
           const float* __restrict__ Mp,
           const float* __restrict__ xzp,
           const float* __restrict__ yzp,
           float* __restrict__ Y) {
    __shared__ unsigned char lds[2 * BUF_B];   // 40960 B

    const int tid  = threadIdx.x;
    const int lane = tid & 63;
    const int wid  = tid >> 6;                 // 0..7
    const int wr   = wid >> 2;                 // row 64-strip
    const int wc   = wid & 3;                  // col 32-strip
    const int fr   = lane & 15;
    const int fq   = lane >> 4;

    // XCD-contiguous bijective swizzle (2048 = 8 * 256); col-tile fastest
    const int b = blockIdx.x;
    const int lid = (b & 7) * 256 + (b >> 3);
    const int row0 = (lid >> 2) * 128;
    const int n0   = (lid & 3) * 128;

    const float xzf = xzp[0];

    // staging maps (512 threads):
    // A tile 128x64 f32: row = tid>>2, 16 f32 at col (tid&3)*16
    // B tile 128x64 i8 : row = tid>>2, 16 B   at col (tid&3)*16
    const int srow = tid >> 2;
    const int scol = (tid & 3) * 16;
    const float* xbase = X + (size_t)(row0 + srow) * K_DIM + scol;
    const unsigned char* wbase = Wb + (size_t)(n0 + srow) * K_DIM + scol;
    const int aoff = srow * LDAB + scol;
    const int boff = TILE_B + srow * LDAB + scol;

    f32x4 ra[2][4];        // two PINNED staging sets (true prefetch distance 2)
    i32x4 rb[2];

    // asm-pinned issue: cannot be sunk or rematerialized by the scheduler.
    auto issue = [&](int t) {
        const int s = t & 1;
        const float* xp = xbase + t * 64;
        const unsigned char* wp = wbase + t * 64;
        asm volatile(
            "global_load_dwordx4 %0, %5, off\n\t"
            "global_load_dwordx4 %1, %5, off offset:16\n\t"
            "global_load_dwordx4 %2, %5, off offset:32\n\t"
            "global_load_dwordx4 %3, %5, off offset:48\n\t"
            "global_load_dwordx4 %4, %6, off"
            : "=v"(ra[s][0]), "=v"(ra[s][1]), "=v"(ra[s][2]), "=v"(ra[s][3]),
              "=v"(rb[s])
            : "v"(xp), "v"(wp));
    };

    auto convwrite = [&](int t, int buf) {
        const int s = t & 1;
        const int ab = buf * BUF_B;
        i32x4 pa;
        #pragma unroll
        for (int q = 0; q < 4; ++q) {
            unsigned int u0 = (unsigned int)((int)(ra[s][q][0] - xzf)) & 0xffu;
            unsigned int u1 = (unsigned int)((int)(ra[s][q][1] - xzf)) & 0xffu;
            unsigned int u2 = (unsigned int)((int)(ra[s][q][2] - xzf)) & 0xffu;
            unsigned int u3 = (unsigned int)((int)(ra[s][q][3] - xzf)) & 0xffu;
            pa[q] = (int)(u0 | (u1 << 8) | (u2 << 16) | (u3 << 24));
        }
        *reinterpret_cast<i32x4*>(&lds[ab + aoff]) = pa;
        *reinterpret_cast<i32x4*>(&lds[ab + boff]) = rb[s];
    };

    // bias folded into accumulator init
    const int c0 = n0 + wc * 32;
    const int bv0 = bias[c0 + fr];
    const int bv1 = bias[c0 + 16 + fr];
    i32x4 acc[4][2];
    #pragma unroll
    for (int m = 0; m < 4; ++m) {
        acc[m][0] = i32x4{bv0, bv0, bv0, bv0};
        acc[m][1] = i32x4{bv1, bv1, bv1, bv1};
    }

    const int aro = (wr * 64 + fr) * LDAB + fq * 16;
    const int bro = TILE_B + (wc * 32 + fr) * LDAB + fq * 16;

    auto compute = [&](int buf) {
        const int ab = buf * BUF_B;
        i32x4 af[4], bf[2];
        #pragma unroll
        for (int m = 0; m < 4; ++m)
            af[m] = *reinterpret_cast<const i32x4*>(&lds[ab + aro + m * 16 * LDAB]);
        #pragma unroll
        for (int n = 0; n < 2; ++n)
            bf[n] = *reinterpret_cast<const i32x4*>(&lds[ab + bro + n * 16 * LDAB]);
        #pragma unroll
        for (int m = 0; m < 4; ++m)
            #pragma unroll
            for (int n = 0; n < 2; ++n)
                acc[m][n] = __builtin_amdgcn_mfma_i32_16x16x64_i8(
                    af[m], bf[n], acc[m][n], 0, 0, 0);
    };

    // lgkm-only barrier: ds ops drained; pinned global prefetch stays in flight.
    auto barrier = [&]() {
        asm volatile("s_waitcnt lgkmcnt(0)" ::: "memory");
        __builtin_amdgcn_s_barrier();
    };
    // counted consumption gate (rule 18: sched_barrier after inline-asm waitcnt)
    auto wait5 = [&]() {
        asm volatile("s_waitcnt vmcnt(5)" ::: "memory");
        __builtin_amdgcn_sched_barrier(0);
    };
    auto wait0 = [&]() {
        asm volatile("s_waitcnt vmcnt(0)" ::: "memory");
        __builtin_amdgcn_sched_barrier(0);
    };

    // prologue: L(0), L(1) in flight (10 + preamble bias loads, which are older)
    issue(0);
    issue(1);
    wait5();                    // L(0) complete; L(1) still flying
    convwrite(0, 0);
    barrier();

    #pragma unroll
    for (int t = 0; t < NT; ++t) {
        if (t + 2 < NT) issue(t + 2);          // pinned issue: 10 in flight
        compute(t & 1);
        if (t + 1 < NT) {
            if (t + 2 < NT) wait5(); else wait0();   // L(t+1) complete
            convwrite(t + 1, (t + 1) & 1);
        }
        barrier();
    }

    // epilogue: y = rintf(acc * M + yz)  (bias pre-folded)
    const float Mv = Mp[0], yz = yzp[0];
    #pragma unroll
    for (int n = 0; n < 2; ++n) {
        const int col = c0 + n * 16 + fr;
        #pragma unroll
        for (int m = 0; m < 4; ++m) {
            const int row = row0 + wr * 64 + m * 16 + fq * 4;
            float* yp = Y + (size_t)row * OUTF + col;
            #pragma unroll
            for (int j = 0; j < 4; ++j)
                yp[(size_t)j * OUTF] = rintf((float)acc[m][n][j] * Mv + yz);
        }
    }
}

extern "C" void kernel_launch(void* const* d_in, const int* in_sizes, int n_in,
                              void* d_out, int out_size, void* d_ws, size_t ws_size,
                              hipStream_t stream) {
    const float* x    = (const float*)d_in[0];
    const int*   w    = (const int*)d_in[1];
    const int*   bias = (const int*)d_in[2];
    const float* M    = (const float*)d_in[3];
    const float* xz   = (const float*)d_in[4];
    const float* wz   = (const float*)d_in[5];
    const float* yz   = (const float*)d_in[6];
    float* y = (float*)d_out;

    unsigned int* Wb = (unsigned int*)d_ws;     // 512*512 i8 = 256 KB

    wprep<<<256, 256, 0, stream>>>(w, Wb, wz);
    qgemm<<<2048, 512, 0, stream>>>(x, (const unsigned char*)Wb, bias, M, xz, yz, y);
}